// Round 13
// baseline (365.505 us; speedup 1.0000x reference)
//
#include <hip/hip_runtime.h>

// B=8, C=64, H=256, W=256
#define BB 8
#define CC 64
#define HH 256
#define WW 256
#define HW (HH*WW)

typedef __attribute__((ext_vector_type(8))) short bf16x8;
typedef __attribute__((ext_vector_type(4))) float f32x4;
typedef __attribute__((ext_vector_type(2))) float f32x2;

__device__ __forceinline__ int reflect_idx(int v, int n) {
    // jnp.pad mode='reflect': -1 -> 1, n -> n-2
    if (v < 0) v = -v;
    if (v >= n) v = 2*n - 2 - v;
    return v;
}

// f32 -> bf16 (RNE) raw bits
__device__ __forceinline__ short f2bf(float f) {
    union { float f; unsigned u; } x; x.f = f;
    unsigned r = (x.u + 0x7fffu + ((x.u >> 16) & 1u)) >> 16;
    return (short)r;
}

__device__ __forceinline__ unsigned cvt_pk_bf16(float lo, float hi) {
    unsigned r;
    asm("v_cvt_pk_bf16_f32 %0, %1, %2" : "=v"(r) : "v"(lo), "v"(hi));
    return r;
}

__global__ __launch_bounds__(256, 3)
void corr_v13_kernel(const float* __restrict__ hs,
                     const float* __restrict__ refLR,
                     const float* __restrict__ w_first,
                     const float* __restrict__ b_first,
                     const float* __restrict__ w_fuse,
                     const float* __restrict__ b_fuse,
                     float* __restrict__ out)
{
    // s_w: reordered bf16 w_fuse [o 64][k' 128 pad 136]; k' = g*32+i,
    //      i<16 -> att col g*16+i, i>=16 -> hs col 48+g*16+i
    __shared__ short s_w[64 * 136];            // 17408 B
    __shared__ short s_fused[4][64 * 40];      // 20480 B per-wave [pix 64][k 32 pad 40]
    // two independent p buffer sets (chunk A / chunk B of each unrolled pair)
    __shared__ float s_pA[4][432];             // ch A: p01 [0..215] | p23 [216..431]
    __shared__ float s_pB[4][432];             // ch B           -> total 51712 B: 3 blk/CU

    const int t = threadIdx.x;
    const int wv = t >> 6, lane = t & 63;

    // XCD swizzle: each XCD owns one batch image
    const int d = (int)blockIdx.x;
    const int lid = (d & 7) * 256 + (d >> 3);
    const int bx = lid & 15, by = (lid >> 4) & 15, b = lid >> 8;

    // ---- stage reordered bf16 weights ----
    #pragma unroll
    for (int rep = 0; rep < 32; ++rep) {
        int idx = t + rep * 256;              // m*128 + k'
        int m = idx >> 7, kp = idx & 127;
        int g = kp >> 5, i = kp & 31;
        int src = (i < 16) ? (g * 16 + i) : (48 + g * 16 + i);
        s_w[m * 136 + kp] = f2bf(w_fuse[m * 128 + src]);
    }
    __syncthreads();   // the only block barrier

    // ---- wave strip: 4 rows x 16 cols within the 16x16 block tile ----
    const int y0 = by * 16 + wv * 4;
    const int x0 = bx * 16;

    // halo: 6 rows x 18 cols = 108 positions; lane owns pos=lane (+ 64+lane if lane<44)
    const bool has1 = lane < 44;
    int g0, g1;
    {
        const int py = lane / 18, px = lane % 18;
        g0 = reflect_idx(y0 + py - 1, HH) * WW + reflect_idx(x0 + px - 1, WW);
    }
    {
        const int pp = 64 + lane;
        const int py = pp / 18, px = pp % 18;
        const int gt = reflect_idx(y0 + py - 1, HH) * WW + reflect_idx(x0 + px - 1, WW);
        g1 = has1 ? gt : g0;
    }
    // lane's own pixel: row pyc (0..3), col pxc (0..15)
    const int pyc = lane >> 4, pxc = lane & 15;
    const int gc = (y0 + pyc) * WW + (x0 + pxc);

    // refLR halo values in registers (loaded once)
    const float* rb = refLR + (size_t)b * 9 * HW;
    float rin0[9], rin1[9];
    #pragma unroll
    for (int j = 0; j < 9; ++j) rin0[j] = rb[(size_t)j * HW + g0];
    #pragma unroll
    for (int j = 0; j < 9; ++j) rin1[j] = rb[(size_t)j * HW + g1];

    // accumulators (bias-initialized). C/D: col=lane&15 (pixel), row=(lane>>4)*4+r
    const int cl = lane & 15, kb = lane >> 4;
    f32x4 acc[4][4];
    #pragma unroll
    for (int mt = 0; mt < 4; ++mt) {
        #pragma unroll
        for (int r = 0; r < 4; ++r) {
            const float bv = b_fuse[mt * 16 + kb * 4 + r];
            #pragma unroll
            for (int nt = 0; nt < 4; ++nt) acc[mt][nt][r] = bv;
        }
    }

    const float* hsb = hs + (size_t)b * CC * HW;
    float* const spA = s_pA[wv];
    float* const spB = s_pB[wv];
    short* const sfw = s_fused[wv];
    const int pb = (pyc * 18 + pxc) * 2;   // box-window base (float index, row stride 18)

    // prefetch chunk 0 and chunk 1 hs values
    float h0A[4], h1A[4], hcA[4], h0B[4], h1B[4], hcB[4];
    #pragma unroll
    for (int cc = 0; cc < 4; ++cc) {
        const float* hpA = hsb + (size_t)cc * HW;
        const float* hpB = hsb + (size_t)(4 + cc) * HW;
        h0A[cc] = hpA[g0]; h1A[cc] = hpA[g1]; hcA[cc] = hpA[gc];
        h0B[cc] = hpB[g0]; h1B[cc] = hpB[g1]; hcB[cc] = hpB[gc];
    }

    #pragma unroll 1
    for (int pr = 0; pr < 8; ++pr) {
        const int chA = pr * 2, chB = pr * 2 + 1;

        // ---- conv A (channels chA*4..+3): two independent halo positions ----
        float prA0[4], prA1[4], hcvA[4];
        #pragma unroll
        for (int cc = 0; cc < 4; ++cc) {
            const int c = chA * 4 + cc;
            float v0 = b_first[c], v1 = v0;
            #pragma unroll
            for (int j = 0; j < 9; ++j) {
                const float w = w_first[c * 9 + j];   // wave-uniform (s_load)
                v0 = fmaf(w, rin0[j], v0);
                v1 = fmaf(w, rin1[j], v1);
            }
            v0 = v0 > 0.f ? v0 : 0.1f * v0;
            v1 = v1 > 0.f ? v1 : 0.1f * v1;
            prA0[cc] = h0A[cc] * v0;
            prA1[cc] = h1A[cc] * v1;
            hcvA[cc] = hcA[cc];
        }
        *(f32x2*)&spA[lane * 2]       = (f32x2){prA0[0], prA0[1]};
        *(f32x2*)&spA[216 + lane * 2] = (f32x2){prA0[2], prA0[3]};
        if (has1) {
            *(f32x2*)&spA[(64 + lane) * 2]       = (f32x2){prA1[0], prA1[1]};
            *(f32x2*)&spA[216 + (64 + lane) * 2] = (f32x2){prA1[2], prA1[3]};
        }

        // ---- conv B (channels chB*4..+3): independent chain fills A's write shadow ----
        float prB0[4], prB1[4], hcvB[4];
        #pragma unroll
        for (int cc = 0; cc < 4; ++cc) {
            const int c = chB * 4 + cc;
            float v0 = b_first[c], v1 = v0;
            #pragma unroll
            for (int j = 0; j < 9; ++j) {
                const float w = w_first[c * 9 + j];
                v0 = fmaf(w, rin0[j], v0);
                v1 = fmaf(w, rin1[j], v1);
            }
            v0 = v0 > 0.f ? v0 : 0.1f * v0;
            v1 = v1 > 0.f ? v1 : 0.1f * v1;
            prB0[cc] = h0B[cc] * v0;
            prB1[cc] = h1B[cc] * v1;
            hcvB[cc] = hcB[cc];
        }
        *(f32x2*)&spB[lane * 2]       = (f32x2){prB0[0], prB0[1]};
        *(f32x2*)&spB[216 + lane * 2] = (f32x2){prB0[2], prB0[3]};
        if (has1) {
            *(f32x2*)&spB[(64 + lane) * 2]       = (f32x2){prB1[0], prB1[1]};
            *(f32x2*)&spB[216 + (64 + lane) * 2] = (f32x2){prB1[2], prB1[3]};
        }

        // single drain covers both chunks' p-writes (R8-proven schedule pin)
        asm volatile("s_waitcnt lgkmcnt(0)" ::: "memory");

        // issue next pair's hs loads (hidden under box/sigmoid/MFMA)
        {
            const int cnA = ((chA + 2) & 15) * 4;
            const int cnB = ((chB + 2) & 15) * 4;
            #pragma unroll
            for (int cc = 0; cc < 4; ++cc) {
                const float* hpA = hsb + (size_t)(cnA + cc) * HW;
                const float* hpB = hsb + (size_t)(cnB + cc) * HW;
                h0A[cc] = hpA[g0]; h1A[cc] = hpA[g1]; hcA[cc] = hpA[gc];
                h0B[cc] = hpB[g0]; h1B[cc] = hpB[g1]; hcB[cc] = hpB[gc];
            }
        }

        // ---- box-sums A and B interleaved (18 independent b64 reads) ----
        f32x2 aA01 = (f32x2){0.f, 0.f}, aA23 = (f32x2){0.f, 0.f};
        f32x2 aB01 = (f32x2){0.f, 0.f}, aB23 = (f32x2){0.f, 0.f};
        #pragma unroll
        for (int dy = 0; dy < 3; ++dy)
            #pragma unroll
            for (int dx = 0; dx < 3; ++dx) {
                const int o = pb + (dy * 18 + dx) * 2;
                aA01 += *(const f32x2*)&spA[o];
                aA23 += *(const f32x2*)&spA[216 + o];
                aB01 += *(const f32x2*)&spB[o];
                aB23 += *(const f32x2*)&spB[216 + o];
            }

        // A-fragment LDS reads for this group (odd pair only; independent)
        bf16x8 af0, af1, af2, af3;
        if (pr & 1) {
            const int g = pr >> 1;
            af0 = *(const bf16x8*)&s_w[(0 * 16 + cl) * 136 + g * 32 + kb * 8];
            af1 = *(const bf16x8*)&s_w[(1 * 16 + cl) * 136 + g * 32 + kb * 8];
            af2 = *(const bf16x8*)&s_w[(2 * 16 + cl) * 136 + g * 32 + kb * 8];
            af3 = *(const bf16x8*)&s_w[(3 * 16 + cl) * 136 + g * 32 + kb * 8];
        }

        // ---- sigmoid gates + packs, both chunks ----
        const float crA[4] = {aA01[0], aA01[1], aA23[0], aA23[1]};
        const float crB[4] = {aB01[0], aB01[1], aB23[0], aB23[1]};
        float avA[4], avB[4];
        #pragma unroll
        for (int cc = 0; cc < 4; ++cc) {
            avA[cc] = __builtin_amdgcn_rcpf(
                1.0f + __builtin_amdgcn_exp2f(crA[cc] * -1.44269504088896f)) * hcvA[cc];
            avB[cc] = __builtin_amdgcn_rcpf(
                1.0f + __builtin_amdgcn_exp2f(crB[cc] * -1.44269504088896f)) * hcvB[cc];
        }
        uint2 uaA, uhA, uaB, uhB;
        uaA.x = cvt_pk_bf16(avA[0], avA[1]);
        uaA.y = cvt_pk_bf16(avA[2], avA[3]);
        uhA.x = cvt_pk_bf16(hcvA[0], hcvA[1]);
        uhA.y = cvt_pk_bf16(hcvA[2], hcvA[3]);
        uaB.x = cvt_pk_bf16(avB[0], avB[1]);
        uaB.y = cvt_pk_bf16(avB[2], avB[3]);
        uhB.x = cvt_pk_bf16(hcvB[0], hcvB[1]);
        uhB.y = cvt_pk_bf16(hcvB[2], hcvB[3]);
        const int k4A = (chA & 3) * 4;
        const int k4B = (chB & 3) * 4;
        *(uint2*)&sfw[lane * 40 + k4A]      = uaA;   // att*hs k-slice, chunk A
        *(uint2*)&sfw[lane * 40 + 16 + k4A] = uhA;   // hs
        *(uint2*)&sfw[lane * 40 + k4B]      = uaB;   // chunk B
        *(uint2*)&sfw[lane * 40 + 16 + k4B] = uhB;

        // ---- group boundary (odd pair): one k=32 MFMA slice ----
        if (pr & 1) {
            asm volatile("s_waitcnt lgkmcnt(0)" ::: "memory");
            #pragma unroll
            for (int nt = 0; nt < 4; ++nt) {
                const bf16x8 bf = *(const bf16x8*)&sfw[(nt * 16 + cl) * 40 + kb * 8];
                acc[0][nt] = __builtin_amdgcn_mfma_f32_16x16x32_bf16(af0, bf, acc[0][nt], 0, 0, 0);
                acc[1][nt] = __builtin_amdgcn_mfma_f32_16x16x32_bf16(af1, bf, acc[1][nt], 0, 0, 0);
                acc[2][nt] = __builtin_amdgcn_mfma_f32_16x16x32_bf16(af2, bf, acc[2][nt], 0, 0, 0);
                acc[3][nt] = __builtin_amdgcn_mfma_f32_16x16x32_bf16(af3, bf, acc[3][nt], 0, 0, 0);
            }
        }
    }

    // ---- epilogue: every store instruction = 4 channel-planes x full 64B lines ----
    float* const ob = out + (size_t)b * CC * HW;
    #pragma unroll
    for (int mt = 0; mt < 4; ++mt) {
        #pragma unroll
        for (int nt = 0; nt < 4; ++nt) {
            #pragma unroll
            for (int r = 0; r < 4; ++r) {
                const int o = mt * 16 + kb * 4 + r;
                ob[(size_t)o * HW + (size_t)(y0 + nt) * WW + (x0 + cl)] = acc[mt][nt][r];
            }
        }
    }
}

extern "C" void kernel_launch(void* const* d_in, const int* in_sizes, int n_in,
                              void* d_out, int out_size, void* d_ws, size_t ws_size,
                              hipStream_t stream) {
    const float* hs      = (const float*)d_in[0];
    const float* refLR   = (const float*)d_in[1];
    const float* w_first = (const float*)d_in[2];
    const float* b_first = (const float*)d_in[3];
    const float* w_fuse  = (const float*)d_in[4];
    const float* b_fuse  = (const float*)d_in[5];
    float* out = (float*)d_out;

    corr_v13_kernel<<<dim3(2048), dim3(256), 0, stream>>>(hs, refLR, w_first, b_first,
                                                          w_fuse, b_fuse, out);
}

// Round 14
// 111.718 us; speedup vs baseline: 3.2717x; 3.2717x over previous
//
#include <hip/hip_runtime.h>

// B=8, C=64, H=256, W=256
#define BB 8
#define CC 64
#define HH 256
#define WW 256
#define HW (HH*WW)

typedef __attribute__((ext_vector_type(8))) short bf16x8;
typedef __attribute__((ext_vector_type(4))) float f32x4;
typedef __attribute__((ext_vector_type(2))) float f32x2;

__device__ __forceinline__ int reflect_idx(int v, int n) {
    // jnp.pad mode='reflect': -1 -> 1, n -> n-2
    if (v < 0) v = -v;
    if (v >= n) v = 2*n - 2 - v;
    return v;
}

// f32 -> bf16 (RNE) raw bits
__device__ __forceinline__ short f2bf(float f) {
    union { float f; unsigned u; } x; x.f = f;
    unsigned r = (x.u + 0x7fffu + ((x.u >> 16) & 1u)) >> 16;
    return (short)r;
}

__device__ __forceinline__ unsigned cvt_pk_bf16(float lo, float hi) {
    unsigned r;
    asm("v_cvt_pk_bf16_f32 %0, %1, %2" : "=v"(r) : "v"(lo), "v"(hi));
    return r;
}

// 8-wave block: amortizes the 17.4KB s_w over 8 waves instead of 4.
// LDS 72192B -> 2 blocks/CU = 16 waves/CU (vs R8's 12). Per-wave body is
// byte-identical to R8 (106us, FETCH 82MB / WRITE 145MB proven-robust).
__global__ __launch_bounds__(512, 2)
void corr_v14_kernel(const float* __restrict__ hs,
                     const float* __restrict__ refLR,
                     const float* __restrict__ w_first,
                     const float* __restrict__ b_first,
                     const float* __restrict__ w_fuse,
                     const float* __restrict__ b_fuse,
                     float* __restrict__ out)
{
    // s_w: reordered bf16 w_fuse [o 64][k' 128 pad 136]; k' = g*32+i,
    //      i<16 -> att col g*16+i, i>=16 -> hs col 48+g*16+i
    __shared__ short s_w[64 * 136];            // 17408 B (shared by 8 waves)
    __shared__ short s_fused[8][64 * 40];      // 40960 B per-wave [pix 64][k 32 pad 40]
    __shared__ float s_p01[8][216];            // p=hs*ref ch0,1 at 108 halo pos (6x18)
    __shared__ float s_p23[8][216];            // ch2,3    -> total 72192 B: 2 blk/CU

    const int t = threadIdx.x;
    const int wv = t >> 6, lane = t & 63;

    // XCD swizzle: each XCD owns one batch image
    const int d = (int)blockIdx.x;
    const int lid = (d & 7) * 128 + (d >> 3);
    const int b = lid >> 7;
    const int r7 = lid & 127;
    const int by = r7 >> 4, bx = r7 & 15;      // 8 y-tiles of 32 rows, 16 x-tiles of 16

    // ---- stage reordered bf16 weights (512 threads -> 16 reps) ----
    #pragma unroll
    for (int rep = 0; rep < 16; ++rep) {
        int idx = t + rep * 512;              // m*128 + k'
        int m = idx >> 7, kp = idx & 127;
        int g = kp >> 5, i = kp & 31;
        int src = (i < 16) ? (g * 16 + i) : (48 + g * 16 + i);
        s_w[m * 136 + kp] = f2bf(w_fuse[m * 128 + src]);
    }
    __syncthreads();   // the only block barrier

    // ---- wave strip: 4 rows x 16 cols; 8 strips stacked = 32x16 block tile ----
    const int y0 = by * 32 + wv * 4;
    const int x0 = bx * 16;

    // halo: 6 rows x 18 cols = 108 positions; lane owns pos=lane (+ 64+lane if lane<44)
    const bool has1 = lane < 44;
    int g0, g1;
    {
        const int py = lane / 18, px = lane % 18;
        g0 = reflect_idx(y0 + py - 1, HH) * WW + reflect_idx(x0 + px - 1, WW);
    }
    {
        const int pp = 64 + lane;
        const int py = pp / 18, px = pp % 18;
        const int gt = reflect_idx(y0 + py - 1, HH) * WW + reflect_idx(x0 + px - 1, WW);
        g1 = has1 ? gt : g0;
    }
    // lane's own pixel: row pyc (0..3), col pxc (0..15)
    const int pyc = lane >> 4, pxc = lane & 15;
    const int gc = (y0 + pyc) * WW + (x0 + pxc);

    // refLR halo values in registers (loaded once)
    const float* rb = refLR + (size_t)b * 9 * HW;
    float rin0[9], rin1[9];
    #pragma unroll
    for (int j = 0; j < 9; ++j) rin0[j] = rb[(size_t)j * HW + g0];
    #pragma unroll
    for (int j = 0; j < 9; ++j) rin1[j] = rb[(size_t)j * HW + g1];

    // accumulators (bias-initialized). C/D: col=lane&15 (pixel), row=(lane>>4)*4+r
    const int cl = lane & 15, kb = lane >> 4;
    f32x4 acc[4][4];
    #pragma unroll
    for (int mt = 0; mt < 4; ++mt) {
        #pragma unroll
        for (int r = 0; r < 4; ++r) {
            const float bv = b_fuse[mt * 16 + kb * 4 + r];
            #pragma unroll
            for (int nt = 0; nt < 4; ++nt) acc[mt][nt][r] = bv;
        }
    }

    const float* hsb = hs + (size_t)b * CC * HW;
    float* const sp01 = s_p01[wv];
    float* const sp23 = s_p23[wv];
    short* const sfw  = s_fused[wv];
    const int pb = (pyc * 18 + pxc) * 2;   // box-window base (float index, row stride 18)

    // prefetch chunk 0 hs values
    float h0[4], h1[4], hc[4];
    #pragma unroll
    for (int cc = 0; cc < 4; ++cc) {
        const float* hp = hsb + (size_t)cc * HW;
        h0[cc] = hp[g0]; h1[cc] = hp[g1]; hc[cc] = hp[gc];
    }

    #pragma unroll 1
    for (int ch = 0; ch < 16; ++ch) {
        const int c0 = ch * 4;

        // ref 1x1 conv + leaky + p-products at owned halo positions
        float pr0[4], pr1[4], hcv[4];
        #pragma unroll
        for (int cc = 0; cc < 4; ++cc) {
            const int c = c0 + cc;
            float v0 = b_first[c], v1 = v0;
            #pragma unroll
            for (int j = 0; j < 9; ++j) {
                const float w = w_first[c * 9 + j];   // wave-uniform (s_load)
                v0 = fmaf(w, rin0[j], v0);
                v1 = fmaf(w, rin1[j], v1);
            }
            v0 = v0 > 0.f ? v0 : 0.1f * v0;
            v1 = v1 > 0.f ? v1 : 0.1f * v1;
            pr0[cc] = h0[cc] * v0;
            pr1[cc] = h1[cc] * v1;
            hcv[cc] = hc[cc];
        }
        *(f32x2*)&sp01[lane * 2] = (f32x2){pr0[0], pr0[1]};
        *(f32x2*)&sp23[lane * 2] = (f32x2){pr0[2], pr0[3]};
        if (has1) {
            *(f32x2*)&sp01[(64 + lane) * 2] = (f32x2){pr1[0], pr1[1]};
            *(f32x2*)&sp23[(64 + lane) * 2] = (f32x2){pr1[2], pr1[3]};
        }
        // wave-local LDS RAW fence (R8-proven schedule pin)
        asm volatile("s_waitcnt lgkmcnt(0)" ::: "memory");

        // 3x3 box-sum of p (row stride 18 -> flat bank profile)
        f32x2 a01 = (f32x2){0.f, 0.f}, a23 = (f32x2){0.f, 0.f};
        #pragma unroll
        for (int dy = 0; dy < 3; ++dy)
            #pragma unroll
            for (int dx = 0; dx < 3; ++dx) {
                const int o = pb + (dy * 18 + dx) * 2;
                a01 += *(const f32x2*)&sp01[o];
                a23 += *(const f32x2*)&sp23[o];
            }

        // issue next chunk's hs loads (hidden under sigmoid/MFMA/next conv)
        {
            const int cn = ((ch + 1) & 15) * 4;
            #pragma unroll
            for (int cc = 0; cc < 4; ++cc) {
                const float* hp = hsb + (size_t)(cn + cc) * HW;
                h0[cc] = hp[g0]; h1[cc] = hp[g1]; hc[cc] = hp[gc];
            }
        }

        // sigmoid gate, bf16 pack, write k-slice of fused
        const float cr[4] = {a01[0], a01[1], a23[0], a23[1]};
        float av[4];
        #pragma unroll
        for (int cc = 0; cc < 4; ++cc)
            av[cc] = __builtin_amdgcn_rcpf(
                1.0f + __builtin_amdgcn_exp2f(cr[cc] * -1.44269504088896f)) * hcv[cc];
        uint2 ua, uh;
        ua.x = cvt_pk_bf16(av[0], av[1]);
        ua.y = cvt_pk_bf16(av[2], av[3]);
        uh.x = cvt_pk_bf16(hcv[0], hcv[1]);
        uh.y = cvt_pk_bf16(hcv[2], hcv[3]);
        const int k4 = (ch & 3) * 4;
        *(uint2*)&sfw[lane * 40 + k4]      = ua;   // att*hs at k = k4..k4+3
        *(uint2*)&sfw[lane * 40 + 16 + k4] = uh;   // hs     at k = 16+k4..

        // group boundary: one k=32 MFMA slice, accumulate
        if ((ch & 3) == 3) {
            asm volatile("s_waitcnt lgkmcnt(0)" ::: "memory");
            const int g = ch >> 2;
            #pragma unroll
            for (int nt = 0; nt < 4; ++nt) {
                const bf16x8 bf = *(const bf16x8*)&sfw[(nt * 16 + cl) * 40 + kb * 8];
                #pragma unroll
                for (int mt = 0; mt < 4; ++mt) {
                    const bf16x8 af = *(const bf16x8*)&s_w[(mt * 16 + cl) * 136 + g * 32 + kb * 8];
                    acc[mt][nt] = __builtin_amdgcn_mfma_f32_16x16x32_bf16(af, bf, acc[mt][nt], 0, 0, 0);
                }
            }
        }
    }

    // ---- epilogue: every store instruction = 4 channel-planes x full 64B lines ----
    float* const ob = out + (size_t)b * CC * HW;
    #pragma unroll
    for (int mt = 0; mt < 4; ++mt) {
        #pragma unroll
        for (int nt = 0; nt < 4; ++nt) {
            #pragma unroll
            for (int r = 0; r < 4; ++r) {
                const int o = mt * 16 + kb * 4 + r;
                ob[(size_t)o * HW + (size_t)(y0 + nt) * WW + (x0 + cl)] = acc[mt][nt][r];
            }
        }
    }
}

extern "C" void kernel_launch(void* const* d_in, const int* in_sizes, int n_in,
                              void* d_out, int out_size, void* d_ws, size_t ws_size,
                              hipStream_t stream) {
    const float* hs      = (const float*)d_in[0];
    const float* refLR   = (const float*)d_in[1];
    const float* w_first = (const float*)d_in[2];
    const float* b_first = (const float*)d_in[3];
    const float* w_fuse  = (const float*)d_in[4];
    const float* b_fuse  = (const float*)d_in[5];
    float* out = (float*)d_out;

    corr_v14_kernel<<<dim3(1024), dim3(512), 0, stream>>>(hs, refLR, w_first, b_first,
                                                          w_fuse, b_fuse, out);
}

// Round 15
// 109.390 us; speedup vs baseline: 3.3413x; 1.0213x over previous
//
#include <hip/hip_runtime.h>

// B=8, C=64, H=256, W=256
#define BB 8
#define CC 64
#define HH 256
#define WW 256
#define HW (HH*WW)

typedef __attribute__((ext_vector_type(8))) short bf16x8;
typedef __attribute__((ext_vector_type(4))) float f32x4;
typedef __attribute__((ext_vector_type(2))) float f32x2;

__device__ __forceinline__ int reflect_idx(int v, int n) {
    // jnp.pad mode='reflect': -1 -> 1, n -> n-2
    if (v < 0) v = -v;
    if (v >= n) v = 2*n - 2 - v;
    return v;
}

// f32 -> bf16 (RNE) raw bits
__device__ __forceinline__ short f2bf(float f) {
    union { float f; unsigned u; } x; x.f = f;
    unsigned r = (x.u + 0x7fffu + ((x.u >> 16) & 1u)) >> 16;
    return (short)r;
}

__device__ __forceinline__ unsigned cvt_pk_bf16(float lo, float hi) {
    unsigned r;
    asm("v_cvt_pk_bf16_f32 %0, %1, %2" : "=v"(r) : "v"(lo), "v"(hi));
    return r;
}

// One R8-identical chunk body, parameterized by the h-register set.
// The ONLY change vs R8: the hs loads issued here target ch+2 (not ch+1) and
// are issued BEFORE the drain -> load-to-use spans two full chunk bodies.
#define CHUNK_BODY(CH_EXPR, H0, H1, HC)                                           \
{                                                                                 \
    const int ch_ = (CH_EXPR);                                                    \
    const int c0_ = ch_ * 4;                                                      \
    float pr0[4], pr1[4], hcv[4];                                                 \
    _Pragma("unroll")                                                             \
    for (int cc = 0; cc < 4; ++cc) {                                              \
        const int c = c0_ + cc;                                                   \
        float v0 = b_first[c], v1 = v0;                                           \
        _Pragma("unroll")                                                         \
        for (int j = 0; j < 9; ++j) {                                             \
            const float w = w_first[c * 9 + j];   /* wave-uniform (s_load) */     \
            v0 = fmaf(w, rin0[j], v0);                                            \
            v1 = fmaf(w, rin1[j], v1);                                            \
        }                                                                         \
        v0 = v0 > 0.f ? v0 : 0.1f * v0;                                           \
        v1 = v1 > 0.f ? v1 : 0.1f * v1;                                           \
        pr0[cc] = H0[cc] * v0;                                                    \
        pr1[cc] = H1[cc] * v1;                                                    \
        hcv[cc] = HC[cc];                                                         \
    }                                                                             \
    *(f32x2*)&sp01[lane * 2] = (f32x2){pr0[0], pr0[1]};                           \
    *(f32x2*)&sp23[lane * 2] = (f32x2){pr0[2], pr0[3]};                           \
    if (has1) {                                                                   \
        *(f32x2*)&sp01[(64 + lane) * 2] = (f32x2){pr1[0], pr1[1]};                \
        *(f32x2*)&sp23[(64 + lane) * 2] = (f32x2){pr1[2], pr1[3]};                \
    }                                                                             \
    /* depth-2 prefetch into the just-consumed set (issued before the drain;      \
       vmcnt is untouched by the lgkm drain -> loads fly in the background) */    \
    {                                                                             \
        const int cn = ((ch_ + 2) & 15) * 4;                                      \
        _Pragma("unroll")                                                         \
        for (int cc = 0; cc < 4; ++cc) {                                          \
            const float* hp = hsb + (size_t)(cn + cc) * HW;                       \
            H0[cc] = hp[g0]; H1[cc] = hp[g1]; HC[cc] = hp[gc];                    \
        }                                                                         \
    }                                                                             \
    /* wave-local LDS RAW fence (R8-proven schedule pin) */                       \
    asm volatile("s_waitcnt lgkmcnt(0)" ::: "memory");                            \
    /* 3x3 box-sum of p (row stride 18 -> flat bank profile) */                   \
    f32x2 a01 = (f32x2){0.f, 0.f}, a23 = (f32x2){0.f, 0.f};                       \
    _Pragma("unroll")                                                             \
    for (int dy = 0; dy < 3; ++dy)                                                \
        _Pragma("unroll")                                                         \
        for (int dx = 0; dx < 3; ++dx) {                                          \
            const int o = pb + (dy * 18 + dx) * 2;                                \
            a01 += *(const f32x2*)&sp01[o];                                       \
            a23 += *(const f32x2*)&sp23[o];                                       \
        }                                                                         \
    /* sigmoid gate, bf16 pack, write k-slice of fused */                         \
    const float cr[4] = {a01[0], a01[1], a23[0], a23[1]};                         \
    float av[4];                                                                  \
    _Pragma("unroll")                                                             \
    for (int cc = 0; cc < 4; ++cc)                                                \
        av[cc] = __builtin_amdgcn_rcpf(                                           \
            1.0f + __builtin_amdgcn_exp2f(cr[cc] * -1.44269504088896f)) * hcv[cc];\
    uint2 ua, uh;                                                                 \
    ua.x = cvt_pk_bf16(av[0], av[1]);                                             \
    ua.y = cvt_pk_bf16(av[2], av[3]);                                             \
    uh.x = cvt_pk_bf16(hcv[0], hcv[1]);                                           \
    uh.y = cvt_pk_bf16(hcv[2], hcv[3]);                                           \
    const int k4 = (ch_ & 3) * 4;                                                 \
    *(uint2*)&sfw[lane * 40 + k4]      = ua;   /* att*hs at k = k4..k4+3 */       \
    *(uint2*)&sfw[lane * 40 + 16 + k4] = uh;   /* hs     at k = 16+k4.. */        \
    /* group boundary: one k=32 MFMA slice, accumulate */                         \
    if ((ch_ & 3) == 3) {                                                         \
        asm volatile("s_waitcnt lgkmcnt(0)" ::: "memory");                        \
        const int g = ch_ >> 2;                                                   \
        _Pragma("unroll")                                                         \
        for (int nt = 0; nt < 4; ++nt) {                                          \
            const bf16x8 bf = *(const bf16x8*)&sfw[(nt * 16 + cl) * 40 + kb * 8]; \
            _Pragma("unroll")                                                     \
            for (int mt = 0; mt < 4; ++mt) {                                      \
                const bf16x8 af = *(const bf16x8*)&s_w[(mt * 16 + cl) * 136 + g * 32 + kb * 8]; \
                acc[mt][nt] = __builtin_amdgcn_mfma_f32_16x16x32_bf16(af, bf, acc[mt][nt], 0, 0, 0); \
            }                                                                     \
        }                                                                         \
    }                                                                             \
}

__global__ __launch_bounds__(256, 3)
void corr_v15_kernel(const float* __restrict__ hs,
                     const float* __restrict__ refLR,
                     const float* __restrict__ w_first,
                     const float* __restrict__ b_first,
                     const float* __restrict__ w_fuse,
                     const float* __restrict__ b_fuse,
                     float* __restrict__ out)
{
    // s_w: reordered bf16 w_fuse [o 64][k' 128 pad 136]; k' = g*32+i,
    //      i<16 -> att col g*16+i, i>=16 -> hs col 48+g*16+i
    __shared__ short s_w[64 * 136];            // 17408 B
    __shared__ short s_fused[4][64 * 40];      // 20480 B per-wave [pix 64][k 32 pad 40]
    __shared__ float s_p01[4][216];            // p=hs*ref ch0,1 at 108 halo pos (6x18)
    __shared__ float s_p23[4][216];            // ch2,3       -> total 44800 B: 3 blk/CU

    const int t = threadIdx.x;
    const int wv = t >> 6, lane = t & 63;

    // XCD swizzle: each XCD owns one batch image
    const int d = (int)blockIdx.x;
    const int lid = (d & 7) * 256 + (d >> 3);
    const int bx = lid & 15, by = (lid >> 4) & 15, b = lid >> 8;

    // ---- stage reordered bf16 weights ----
    #pragma unroll
    for (int rep = 0; rep < 32; ++rep) {
        int idx = t + rep * 256;              // m*128 + k'
        int m = idx >> 7, kp = idx & 127;
        int g = kp >> 5, i = kp & 31;
        int src = (i < 16) ? (g * 16 + i) : (48 + g * 16 + i);
        s_w[m * 136 + kp] = f2bf(w_fuse[m * 128 + src]);
    }
    __syncthreads();   // the only block barrier

    // ---- wave strip: 4 rows x 16 cols within the 16x16 block tile ----
    const int y0 = by * 16 + wv * 4;
    const int x0 = bx * 16;

    // halo: 6 rows x 18 cols = 108 positions; lane owns pos=lane (+ 64+lane if lane<44)
    const bool has1 = lane < 44;
    int g0, g1;
    {
        const int py = lane / 18, px = lane % 18;
        g0 = reflect_idx(y0 + py - 1, HH) * WW + reflect_idx(x0 + px - 1, WW);
    }
    {
        const int pp = 64 + lane;
        const int py = pp / 18, px = pp % 18;
        const int gt = reflect_idx(y0 + py - 1, HH) * WW + reflect_idx(x0 + px - 1, WW);
        g1 = has1 ? gt : g0;
    }
    // lane's own pixel: row pyc (0..3), col pxc (0..15)
    const int pyc = lane >> 4, pxc = lane & 15;
    const int gc = (y0 + pyc) * WW + (x0 + pxc);

    // refLR halo values in registers (loaded once)
    const float* rb = refLR + (size_t)b * 9 * HW;
    float rin0[9], rin1[9];
    #pragma unroll
    for (int j = 0; j < 9; ++j) rin0[j] = rb[(size_t)j * HW + g0];
    #pragma unroll
    for (int j = 0; j < 9; ++j) rin1[j] = rb[(size_t)j * HW + g1];

    // accumulators (bias-initialized). C/D: col=lane&15 (pixel), row=(lane>>4)*4+r
    const int cl = lane & 15, kb = lane >> 4;
    f32x4 acc[4][4];
    #pragma unroll
    for (int mt = 0; mt < 4; ++mt) {
        #pragma unroll
        for (int r = 0; r < 4; ++r) {
            const float bv = b_fuse[mt * 16 + kb * 4 + r];
            #pragma unroll
            for (int nt = 0; nt < 4; ++nt) acc[mt][nt][r] = bv;
        }
    }

    const float* hsb = hs + (size_t)b * CC * HW;
    float* const sp01 = s_p01[wv];
    float* const sp23 = s_p23[wv];
    short* const sfw  = s_fused[wv];
    const int pb = (pyc * 18 + pxc) * 2;   // box-window base (float index, row stride 18)

    // ---- prologue: prefetch chunk 0 (set A) and chunk 1 (set B) ----
    float h0A[4], h1A[4], hcA[4], h0B[4], h1B[4], hcB[4];
    #pragma unroll
    for (int cc = 0; cc < 4; ++cc) {
        const float* hpA = hsb + (size_t)cc * HW;
        const float* hpB = hsb + (size_t)(4 + cc) * HW;
        h0A[cc] = hpA[g0]; h1A[cc] = hpA[g1]; hcA[cc] = hpA[gc];
        h0B[cc] = hpB[g0]; h1B[cc] = hpB[g1]; hcB[cc] = hpB[gc];
    }

    #pragma unroll 1
    for (int pr = 0; pr < 8; ++pr) {
        CHUNK_BODY(pr * 2,     h0A, h1A, hcA);   // even chunk, register set A
        CHUNK_BODY(pr * 2 + 1, h0B, h1B, hcB);   // odd  chunk, register set B
    }

    // ---- epilogue: every store instruction = 4 channel-planes x full 64B lines ----
    float* const ob = out + (size_t)b * CC * HW;
    #pragma unroll
    for (int mt = 0; mt < 4; ++mt) {
        #pragma unroll
        for (int nt = 0; nt < 4; ++nt) {
            #pragma unroll
            for (int r = 0; r < 4; ++r) {
                const int o = mt * 16 + kb * 4 + r;
                ob[(size_t)o * HW + (size_t)(y0 + nt) * WW + (x0 + cl)] = acc[mt][nt][r];
            }
        }
    }
}

extern "C" void kernel_launch(void* const* d_in, const int* in_sizes, int n_in,
                              void* d_out, int out_size, void* d_ws, size_t ws_size,
                              hipStream_t stream) {
    const float* hs      = (const float*)d_in[0];
    const float* refLR   = (const float*)d_in[1];
    const float* w_first = (const float*)d_in[2];
    const float* b_first = (const float*)d_in[3];
    const float* w_fuse  = (const float*)d_in[4];
    const float* b_fuse  = (const float*)d_in[5];
    float* out = (float*)d_out;

    corr_v15_kernel<<<dim3(2048), dim3(256), 0, stream>>>(hs, refLR, w_first, b_first,
                                                          w_fuse, b_fuse, out);
}